// Round 2
// baseline (445.726 us; speedup 1.0000x reference)
//
#include <hip/hip_runtime.h>
#include <hip/hip_bf16.h>

#define N_TOKENS 16384
#define DIM 4096
#define N_EXP 64

// d_out layout (all float32):
//   [0, 32768)              topk_experts as float  [token][2]
//   [32768, 65536)          combine_weight         [token][2]
//   [65536, 65536+1048576)  scores                 [token][64]
//   [1114112]               load_balance_loss
//   [1114113]               z_loss
#define OFF_W   (N_TOKENS * 2)
#define OFF_S   (N_TOKENS * 4)
#define OFF_LBL (N_TOKENS * 4 + N_TOKENS * N_EXP)
#define OFF_Z   (OFF_LBL + 1)

// ws layout: [0..63] me partial sums, [64..127] ce partial counts, [128] z partial sum

__global__ __launch_bounds__(512) void router_kernel(
    const float* __restrict__ x, const float* __restrict__ w,
    float* __restrict__ out, float* __restrict__ ws)
{
  __shared__ float lds[64 * 65];  // [token][expert], row stride 65 -> conflict-free
  const int tid  = threadIdx.x;
  const int lane = tid & 63;
  const int wv   = __builtin_amdgcn_readfirstlane(tid >> 6);  // wave-uniform expert group
  const int token = blockIdx.x * 64 + lane;

  const float* xr = x + (size_t)token * DIM;
  const float* wb = w + (size_t)(wv * 8) * DIM;

  float acc[8];
#pragma unroll
  for (int e = 0; e < 8; ++e) acc[e] = 0.0f;

  for (int k0 = 0; k0 < DIM; k0 += 16) {
    const float4 xa = *(const float4*)(xr + k0);
    const float4 xb = *(const float4*)(xr + k0 + 4);
    const float4 xc = *(const float4*)(xr + k0 + 8);
    const float4 xd = *(const float4*)(xr + k0 + 12);
    const float* wr0 = wb + k0;
#pragma unroll
    for (int e = 0; e < 8; ++e) {
      const float* wr = wr0 + (size_t)e * DIM;  // wave-uniform address -> s_load
      float s = acc[e];
      s = fmaf(xa.x, wr[0],  s);
      s = fmaf(xa.y, wr[1],  s);
      s = fmaf(xa.z, wr[2],  s);
      s = fmaf(xa.w, wr[3],  s);
      s = fmaf(xb.x, wr[4],  s);
      s = fmaf(xb.y, wr[5],  s);
      s = fmaf(xb.z, wr[6],  s);
      s = fmaf(xb.w, wr[7],  s);
      s = fmaf(xc.x, wr[8],  s);
      s = fmaf(xc.y, wr[9],  s);
      s = fmaf(xc.z, wr[10], s);
      s = fmaf(xc.w, wr[11], s);
      s = fmaf(xd.x, wr[12], s);
      s = fmaf(xd.y, wr[13], s);
      s = fmaf(xd.z, wr[14], s);
      s = fmaf(xd.w, wr[15], s);
      acc[e] = s;
    }
  }

  // stash logits: lane writes 8 consecutive floats at row `lane` (stride 65 -> banks differ)
#pragma unroll
  for (int e = 0; e < 8; ++e) lds[lane * 65 + wv * 8 + e] = acc[e];
  __syncthreads();

  if (wv == 0) {
    // lane owns one token: full softmax + top-2 + z-loss
    float v[64];
#pragma unroll
    for (int e = 0; e < 64; ++e) v[e] = lds[lane * 65 + e];
    float m = v[0];
#pragma unroll
    for (int e = 1; e < 64; ++e) m = fmaxf(m, v[e]);
    float sum = 0.f;
#pragma unroll
    for (int e = 0; e < 64; ++e) { v[e] = expf(v[e] - m); sum += v[e]; }
    const float inv = 1.0f / sum;
    float m1 = -1.f, m2 = -1.f;
    int   i1 = 0,    i2 = 0;
#pragma unroll
    for (int e = 0; e < 64; ++e) {
      float sc = v[e] * inv;
      lds[lane * 65 + e] = sc;
      if (sc > m1)      { m2 = m1; i2 = i1; m1 = sc; i1 = e; }
      else if (sc > m2) { m2 = sc; i2 = e; }
    }
    out[2 * token]         = (float)i1;
    out[2 * token + 1]     = (float)i2;
    out[OFF_W + 2 * token]     = m1;
    out[OFF_W + 2 * token + 1] = m2;

    float lse = m + logf(sum);
    float z = lse * lse;
#pragma unroll
    for (int off = 32; off > 0; off >>= 1) z += __shfl_down(z, off);
    if (lane == 0) atomicAdd(ws + 128, z);
  }
  __syncthreads();

  // coalesced scores store for this block's 64 tokens
  float* outS = out + OFF_S + (size_t)blockIdx.x * 64 * 64;
  for (int i = tid; i < 64 * 64; i += 512) {
    outS[i] = lds[(i >> 6) * 65 + (i & 63)];
  }

  // per-expert partial me / ce for this block's tokens
  if (wv == 0) {
    float sm = 0.f, cn = 0.f;
#pragma unroll
    for (int t = 0; t < 64; ++t) {
      float sc = lds[t * 65 + lane];
      sm += sc;
      cn += (sc > 0.f) ? 1.f : 0.f;
    }
    atomicAdd(ws + lane, sm);
    atomicAdd(ws + 64 + lane, cn);
  }
}

__global__ void finalize_kernel(const float* __restrict__ ws, float* __restrict__ out) {
  const int l = threadIdx.x;  // 64 threads
  const float invT = 1.0f / (float)N_TOKENS;
  float me = ws[l] * invT;
  float ce = ws[64 + l] * invT;
  float p = me * ce;
#pragma unroll
  for (int off = 32; off > 0; off >>= 1) p += __shfl_down(p, off);
  if (l == 0) {
    out[OFF_LBL] = p * (float)N_EXP;
    out[OFF_Z]   = ws[128] * invT;
  }
}

extern "C" void kernel_launch(void* const* d_in, const int* in_sizes, int n_in,
                              void* d_out, int out_size, void* d_ws, size_t ws_size,
                              hipStream_t stream) {
  const float* x = (const float*)d_in[0];
  const float* w = (const float*)d_in[1];
  float* out = (float*)d_out;
  float* ws  = (float*)d_ws;

  hipMemsetAsync(d_ws, 0, 129 * sizeof(float), stream);
  router_kernel<<<N_TOKENS / 64, 512, 0, stream>>>(x, w, out, ws);
  finalize_kernel<<<1, 64, 0, stream>>>(ws, out);
}

// Round 3
// 345.271 us; speedup vs baseline: 1.2909x; 1.2909x over previous
//
#include <hip/hip_runtime.h>
#include <hip/hip_bf16.h>

#define N_TOKENS 16384
#define DIM 4096
#define KH 2048      // K half per wave
#define N_EXP 64

// d_out layout (all float32):
//   [0, 32768)              topk_experts as float  [token][2]
//   [32768, 65536)          combine_weight         [token][2]
//   [65536, 65536+1048576)  scores                 [token][64]
//   [1114112]               load_balance_loss
//   [1114113]               z_loss
#define OFF_W   (N_TOKENS * 2)
#define OFF_S   (N_TOKENS * 4)
#define OFF_LBL (N_TOKENS * 4 + N_TOKENS * N_EXP)
#define OFF_Z   (OFF_LBL + 1)

// ws layout: [0..63] me partial sums, [64..127] ce partial counts, [128] z partial sum

__global__ __launch_bounds__(1024) void router_kernel(
    const float* __restrict__ x, const float* __restrict__ w,
    float* __restrict__ out, float* __restrict__ ws)
{
  __shared__ float l0[64 * 65];  // kh=0 partials -> full logits -> scores
  __shared__ float l1[64 * 65];  // kh=1 partials
  const int tid  = threadIdx.x;
  const int lane = tid & 63;
  const int wv   = __builtin_amdgcn_readfirstlane(tid >> 6);  // 0..15, wave-uniform
  const int eg   = wv & 7;   // expert group: 8 experts
  const int kh   = wv >> 3;  // K half: 0 or 1
  const int token = blockIdx.x * 64 + lane;

  const float* xr = x + (size_t)token * DIM + kh * KH;
  const float* wb = w + (size_t)(eg * 8) * DIM + kh * KH;  // wave-uniform

  float acc[8];
#pragma unroll
  for (int e = 0; e < 8; ++e) acc[e] = 0.0f;

  // register double-buffer for the per-lane x stream (64 B / iter)
  float4 ca = *(const float4*)(xr);
  float4 cb = *(const float4*)(xr + 4);
  float4 cc = *(const float4*)(xr + 8);
  float4 cd = *(const float4*)(xr + 12);

  for (int k0 = 0; k0 < KH; k0 += 16) {
    const int kn = (k0 + 16 < KH) ? (k0 + 16) : k0;  // clamped prefetch (branchless)
    float4 na = *(const float4*)(xr + kn);
    float4 nb = *(const float4*)(xr + kn + 4);
    float4 nc = *(const float4*)(xr + kn + 8);
    float4 nd = *(const float4*)(xr + kn + 12);

    const float* wr0 = wb + k0;
#pragma unroll
    for (int e = 0; e < 8; ++e) {
      const float* wr = wr0 + (size_t)e * DIM;  // wave-uniform -> s_load
      float s = acc[e];
      s = fmaf(ca.x, wr[0],  s);
      s = fmaf(ca.y, wr[1],  s);
      s = fmaf(ca.z, wr[2],  s);
      s = fmaf(ca.w, wr[3],  s);
      s = fmaf(cb.x, wr[4],  s);
      s = fmaf(cb.y, wr[5],  s);
      s = fmaf(cb.z, wr[6],  s);
      s = fmaf(cb.w, wr[7],  s);
      s = fmaf(cc.x, wr[8],  s);
      s = fmaf(cc.y, wr[9],  s);
      s = fmaf(cc.z, wr[10], s);
      s = fmaf(cc.w, wr[11], s);
      s = fmaf(cd.x, wr[12], s);
      s = fmaf(cd.y, wr[13], s);
      s = fmaf(cd.z, wr[14], s);
      s = fmaf(cd.w, wr[15], s);
      acc[e] = s;
    }
    ca = na; cb = nb; cc = nc; cd = nd;
  }

  // stash partial logits (stride 65 -> conflict-free)
  float* dst = (kh == 0) ? l0 : l1;
#pragma unroll
  for (int e = 0; e < 8; ++e) dst[lane * 65 + eg * 8 + e] = acc[e];
  __syncthreads();

  // combine the two K halves: 4096 elems over 1024 threads
  for (int i = tid; i < 64 * 64; i += 1024) {
    const int t = i >> 6, e = i & 63;
    l0[t * 65 + e] += l1[t * 65 + e];
  }
  __syncthreads();

  if (wv == 0) {
    // lane owns one token: full softmax + top-2 + z-loss
    float v[64];
#pragma unroll
    for (int e = 0; e < 64; ++e) v[e] = l0[lane * 65 + e];
    float m = v[0];
#pragma unroll
    for (int e = 1; e < 64; ++e) m = fmaxf(m, v[e]);
    float sum = 0.f;
#pragma unroll
    for (int e = 0; e < 64; ++e) { v[e] = expf(v[e] - m); sum += v[e]; }
    const float inv = 1.0f / sum;
    float m1 = -1.f, m2 = -1.f;
    int   i1 = 0,    i2 = 0;
#pragma unroll
    for (int e = 0; e < 64; ++e) {
      float sc = v[e] * inv;
      l0[lane * 65 + e] = sc;
      if (sc > m1)      { m2 = m1; i2 = i1; m1 = sc; i1 = e; }
      else if (sc > m2) { m2 = sc; i2 = e; }
    }
    out[2 * token]         = (float)i1;
    out[2 * token + 1]     = (float)i2;
    out[OFF_W + 2 * token]     = m1;
    out[OFF_W + 2 * token + 1] = m2;

    float lse = m + logf(sum);
    float z = lse * lse;
#pragma unroll
    for (int off = 32; off > 0; off >>= 1) z += __shfl_down(z, off);
    if (lane == 0) atomicAdd(ws + 128, z);
  }
  __syncthreads();

  // coalesced scores store for this block's 64 tokens
  float* outS = out + OFF_S + (size_t)blockIdx.x * 64 * 64;
  for (int i = tid; i < 64 * 64; i += 1024) {
    outS[i] = l0[(i >> 6) * 65 + (i & 63)];
  }

  // per-expert partial me / ce for this block's tokens
  if (wv == 0) {
    float sm = 0.f, cn = 0.f;
#pragma unroll
    for (int t = 0; t < 64; ++t) {
      float sc = l0[t * 65 + lane];
      sm += sc;
      cn += (sc > 0.f) ? 1.f : 0.f;
    }
    atomicAdd(ws + lane, sm);
    atomicAdd(ws + 64 + lane, cn);
  }
}

__global__ void finalize_kernel(const float* __restrict__ ws, float* __restrict__ out) {
  const int l = threadIdx.x;  // 64 threads
  const float invT = 1.0f / (float)N_TOKENS;
  float me = ws[l] * invT;
  float ce = ws[64 + l] * invT;
  float p = me * ce;
#pragma unroll
  for (int off = 32; off > 0; off >>= 1) p += __shfl_down(p, off);
  if (l == 0) {
    out[OFF_LBL] = p * (float)N_EXP;
    out[OFF_Z]   = ws[128] * invT;
  }
}

extern "C" void kernel_launch(void* const* d_in, const int* in_sizes, int n_in,
                              void* d_out, int out_size, void* d_ws, size_t ws_size,
                              hipStream_t stream) {
  const float* x = (const float*)d_in[0];
  const float* w = (const float*)d_in[1];
  float* out = (float*)d_out;
  float* ws  = (float*)d_ws;

  hipMemsetAsync(d_ws, 0, 129 * sizeof(float), stream);
  router_kernel<<<N_TOKENS / 64, 1024, 0, stream>>>(x, w, out, ws);
  finalize_kernel<<<1, 64, 0, stream>>>(ws, out);
}

// Round 6
// 166.541 us; speedup vs baseline: 2.6764x; 2.0732x over previous
//
#include <hip/hip_runtime.h>
#include <hip/hip_bf16.h>

typedef __attribute__((ext_vector_type(8))) short bf16x8;
typedef __attribute__((ext_vector_type(4))) float f32x4;

#define N_TOKENS 16384
#define DIM 4096
#define KH 2048      // K half per wave
#define N_EXP 64

// d_out layout (all float32):
//   [0, 32768)              topk_experts as float  [token][2]
//   [32768, 65536)          combine_weight         [token][2]
//   [65536, 65536+1048576)  scores                 [token][64]
//   [1114112]               load_balance_loss
//   [1114113]               z_loss
#define OFF_W   (N_TOKENS * 2)
#define OFF_S   (N_TOKENS * 4)
#define OFF_LBL (N_TOKENS * 4 + N_TOKENS * N_EXP)
#define OFF_Z   (OFF_LBL + 1)

// ws layout: [0..63] me partial sums, [64..127] ce partial counts, [128] z partial sum

// split one fp32 into hi bf16 + lo bf16 (RNE both): f ≈ hi + lo, |err| ~ 2^-17 |f|
__device__ __forceinline__ void split2(float f, short* hi, short* lo) {
  unsigned short h = __builtin_bit_cast(unsigned short, __float2bfloat16(f));
  float hf = __uint_as_float(((unsigned)h) << 16);
  unsigned short l = __builtin_bit_cast(unsigned short, __float2bfloat16(f - hf));
  *hi = (short)h;
  *lo = (short)l;
}

__device__ __forceinline__ void split8(const float4& f0, const float4& f1,
                                       bf16x8& hi, bf16x8& lo) {
  short h[8], l[8];
  split2(f0.x, &h[0], &l[0]);
  split2(f0.y, &h[1], &l[1]);
  split2(f0.z, &h[2], &l[2]);
  split2(f0.w, &h[3], &l[3]);
  split2(f1.x, &h[4], &l[4]);
  split2(f1.y, &h[5], &l[5]);
  split2(f1.z, &h[6], &l[6]);
  split2(f1.w, &h[7], &l[7]);
#pragma unroll
  for (int i = 0; i < 8; ++i) { hi[i] = h[i]; lo[i] = l[i]; }
}

__global__ __launch_bounds__(512) void router_kernel(
    const float* __restrict__ x, const float* __restrict__ w,
    float* __restrict__ out, float* __restrict__ ws)
{
  __shared__ float l0[64 * 65];  // kh=0 partial logits -> full logits -> scores
  __shared__ float l1[64 * 65];  // kh=1 partial logits
  const int tid  = threadIdx.x;
  const int lane = tid & 63;
  const int wv   = __builtin_amdgcn_readfirstlane(tid >> 6);  // 0..7, wave-uniform
  const int g    = wv & 3;   // token sub-group (16 tokens each)
  const int kh   = wv >> 2;  // K half: 0 or 1
  const int half = lane >> 4;  // 0..3  -> k-subblock of 8
  const int r15  = lane & 15;

  const int tokL = g * 16;                       // local token base (within block's 64)
  const int tok0 = blockIdx.x * 64 + tokL;       // global token base for this wave

  // A fragment source: x[tok0 + r15][kh*KH + half*8 + j + k0]
  const float* xp = x + (size_t)(tok0 + r15) * DIM + kh * KH + half * 8;
  // B fragment source: w[n*16 + r15][kh*KH + half*8 + j + k0]
  const float* wp = w + (size_t)r15 * DIM + kh * KH + half * 8;
#define WROW(n) (wp + (size_t)(n) * 16 * DIM)

  f32x4 acc[4];
#pragma unroll
  for (int n = 0; n < 4; ++n) acc[n] = (f32x4){0.f, 0.f, 0.f, 0.f};

  // current-step fp32 buffers (register double-buffered against the next step)
  float4 cxa = *(const float4*)(xp);
  float4 cxb = *(const float4*)(xp + 4);
  float4 cwa[4], cwb[4];
#pragma unroll
  for (int n = 0; n < 4; ++n) {
    cwa[n] = *(const float4*)(WROW(n));
    cwb[n] = *(const float4*)(WROW(n) + 4);
  }

  for (int k0 = 0; k0 < KH; k0 += 32) {
    const int kn = (k0 + 32 < KH) ? (k0 + 32) : k0;  // clamped prefetch
    float4 nxa = *(const float4*)(xp + kn);
    float4 nxb = *(const float4*)(xp + kn + 4);
    float4 nwa[4], nwb[4];
#pragma unroll
    for (int n = 0; n < 4; ++n) {
      nwa[n] = *(const float4*)(WROW(n) + kn);
      nwb[n] = *(const float4*)(WROW(n) + kn + 4);
    }

    // convert current step to bf16 hi/lo fragments
    bf16x8 a_hi, a_lo;
    split8(cxa, cxb, a_hi, a_lo);
    bf16x8 b_hi[4], b_lo[4];
#pragma unroll
    for (int n = 0; n < 4; ++n) split8(cwa[n], cwb[n], b_hi[n], b_lo[n]);

    // 3-pass split-bf16 MFMA: hi*hi + lo*hi + hi*lo  (lo*lo dropped, ~2^-18 rel)
#pragma unroll
    for (int n = 0; n < 4; ++n)
      acc[n] = __builtin_amdgcn_mfma_f32_16x16x32_bf16(a_hi, b_hi[n], acc[n], 0, 0, 0);
#pragma unroll
    for (int n = 0; n < 4; ++n)
      acc[n] = __builtin_amdgcn_mfma_f32_16x16x32_bf16(a_lo, b_hi[n], acc[n], 0, 0, 0);
#pragma unroll
    for (int n = 0; n < 4; ++n)
      acc[n] = __builtin_amdgcn_mfma_f32_16x16x32_bf16(a_hi, b_lo[n], acc[n], 0, 0, 0);

    cxa = nxa; cxb = nxb;
#pragma unroll
    for (int n = 0; n < 4; ++n) { cwa[n] = nwa[n]; cwb[n] = nwb[n]; }
  }

  // scatter partial logits to LDS.  C layout: row = half*4 + r (token), col = r15 (expert)
  float* dst = kh ? l1 : l0;
#pragma unroll
  for (int n = 0; n < 4; ++n) {
#pragma unroll
    for (int r = 0; r < 4; ++r) {
      dst[(tokL + half * 4 + r) * 65 + n * 16 + r15] = acc[n][r];
    }
  }
  __syncthreads();

  // combine the two K halves: 4096 elems over 512 threads
  for (int i = tid; i < 64 * 64; i += 512) {
    const int t = i >> 6, e = i & 63;
    l0[t * 65 + e] += l1[t * 65 + e];
  }
  __syncthreads();

  if (wv == 0) {
    // lane owns one token: full softmax + top-2 + z-loss
    const int token = blockIdx.x * 64 + lane;
    float v[64];
#pragma unroll
    for (int e = 0; e < 64; ++e) v[e] = l0[lane * 65 + e];
    float m = v[0];
#pragma unroll
    for (int e = 1; e < 64; ++e) m = fmaxf(m, v[e]);
    float sum = 0.f;
#pragma unroll
    for (int e = 0; e < 64; ++e) { v[e] = expf(v[e] - m); sum += v[e]; }
    const float inv = 1.0f / sum;
    float m1 = -1.f, m2 = -1.f;
    int   i1 = 0,    i2 = 0;
#pragma unroll
    for (int e = 0; e < 64; ++e) {
      float sc = v[e] * inv;
      l0[lane * 65 + e] = sc;
      if (sc > m1)      { m2 = m1; i2 = i1; m1 = sc; i1 = e; }
      else if (sc > m2) { m2 = sc; i2 = e; }
    }
    out[2 * token]         = (float)i1;
    out[2 * token + 1]     = (float)i2;
    out[OFF_W + 2 * token]     = m1;
    out[OFF_W + 2 * token + 1] = m2;

    float lse = m + logf(sum);
    float z = lse * lse;
#pragma unroll
    for (int off = 32; off > 0; off >>= 1) z += __shfl_down(z, off);
    if (lane == 0) atomicAdd(ws + 128, z);
  }
  __syncthreads();

  // coalesced scores store for this block's 64 tokens
  float* outS = out + OFF_S + (size_t)blockIdx.x * 64 * 64;
  for (int i = tid; i < 64 * 64; i += 512) {
    outS[i] = l0[(i >> 6) * 65 + (i & 63)];
  }

  // per-expert partial me / ce for this block's tokens
  if (wv == 0) {
    float sm = 0.f, cn = 0.f;
#pragma unroll
    for (int t = 0; t < 64; ++t) {
      float sc = l0[t * 65 + lane];
      sm += sc;
      cn += (sc > 0.f) ? 1.f : 0.f;
    }
    atomicAdd(ws + lane, sm);
    atomicAdd(ws + 64 + lane, cn);
  }
}

__global__ void finalize_kernel(const float* __restrict__ ws, float* __restrict__ out) {
  const int l = threadIdx.x;  // 64 threads
  const float invT = 1.0f / (float)N_TOKENS;
  float me = ws[l] * invT;
  float ce = ws[64 + l] * invT;
  float p = me * ce;
#pragma unroll
  for (int off = 32; off > 0; off >>= 1) p += __shfl_down(p, off);
  if (l == 0) {
    out[OFF_LBL] = p * (float)N_EXP;
    out[OFF_Z]   = ws[128] * invT;
  }
}

extern "C" void kernel_launch(void* const* d_in, const int* in_sizes, int n_in,
                              void* d_out, int out_size, void* d_ws, size_t ws_size,
                              hipStream_t stream) {
  const float* x = (const float*)d_in[0];
  const float* w = (const float*)d_in[1];
  float* out = (float*)d_out;
  float* ws  = (float*)d_ws;

  (void)hipMemsetAsync(d_ws, 0, 129 * sizeof(float), stream);
  router_kernel<<<N_TOKENS / 64, 512, 0, stream>>>(x, w, out, ws);
  finalize_kernel<<<1, 64, 0, stream>>>(ws, out);
}